// Round 7
// baseline (146.897 us; speedup 1.0000x reference)
//
#include <hip/hip_runtime.h>
#include <cstddef>

#define D 128

static constexpr float A_SCALE = 0.1f;
static constexpr float B_SCALE = 0.1f;
static constexpr float AB = A_SCALE * B_SCALE;   // fold both scales into dot weights

typedef float nfloat4 __attribute__((ext_vector_type(4)));   // native vec for NT builtins

__device__ __forceinline__ float4 ldf4(const float* p) {
    return *reinterpret_cast<const float4*>(p);
}

__device__ __forceinline__ void ntst4(float* p, float a, float b, float c, float d) {
    nfloat4 v; v.x = a; v.y = b; v.z = c; v.w = d;
    __builtin_nontemporal_store(v, reinterpret_cast<nfloat4*>(p));
}

// DPP row-rotate fetch: dst[i] = src[(i+N) mod 16] within each 16-lane row.
// ROW_ROR:N ctrl = 0x120+N. Pure VALU (no DS pipe).
template<int CTRL>
__device__ __forceinline__ float dpp_ror(float x) {
    int xi = __builtin_bit_cast(int, x);
    int yi = __builtin_amdgcn_update_dpp(0, xi, CTRL, 0xF, 0xF, true);
    return __builtin_bit_cast(float, yi);
}

// Rotate-allreduce over a 16-lane row: rotations by 1,2,4,8 -> every lane
// holds the 16-lane sum. 8 VALU ops, zero DS ops.
__device__ __forceinline__ float row16_allreduce(float v) {
    v += dpp_ror<0x121>(v);
    v += dpp_ror<0x122>(v);
    v += dpp_ror<0x124>(v);
    v += dpp_ror<0x128>(v);
    return v;
}

// ---------------------------------------------------------------------------
// Pass 1 (merged user+item): global reduction partials only (dots are
// recomputed in pass 2 -- no dots round-trip).
// Wave layout: 16 lanes x 8 floats per row -> wave = 4 rows/iter. FORWARD
// sweep. Block split user:item = 1248:800 (~3:2 = U:I) so both sides finish
// together. 6 dots/4-rows: user s={0,2} (a_xx, a_yxy), item s={1,3}
// (a_xyy, a_yy). acc[b] pairs d[b][0], acc[3+b] pairs d[b][1] (raw-x
// accumulation, A_SCALE applied at partial write).
// partial layout: partial[lb][t], contiguous 3KB per block.
// ---------------------------------------------------------------------------
__global__ __launch_bounds__(256) void pass1_kernel(
    const float* __restrict__ ue, const float* __restrict__ ie,
    const int* __restrict__ uids, const int* __restrict__ iids,
    int U, int I, const float* __restrict__ w_vec,
    const float* __restrict__ edge_emb,
    float* __restrict__ part_u, float* __restrict__ part_i,
    int nbu, int nbi)
{
    const bool isUser = (int)blockIdx.x < nbu;
    const int lb = isUser ? blockIdx.x : (blockIdx.x - nbu);
    const int nb = isUser ? nbu : nbi;
    const float* emb = isUser ? ue : ie;
    const int* ids   = isUser ? uids : iids;
    const int nrows  = isUser ? U : I;
    float* partial   = isUser ? part_u : part_i;

    const int lane = threadIdx.x & 63;
    const int grp  = lane >> 4;          // row within quad
    const int li   = lane & 15;
    const int col  = li << 2;            // cols [col,col+4) and [col+64,col+68)
    const int wv_  = threadIdx.x >> 6;   // wave in block

    // ew[b][j][k] = w_vec[b][s][k] * e_raw[k] * A*B
    float ew[3][2][8];
    {
        float4 e0 = ldf4(edge_emb + col);
        float4 e1 = ldf4(edge_emb + 64 + col);
        const float ee[8] = {e0.x*AB, e0.y*AB, e0.z*AB, e0.w*AB,
                             e1.x*AB, e1.y*AB, e1.z*AB, e1.w*AB};
#pragma unroll
        for (int b = 0; b < 3; ++b)
#pragma unroll
            for (int j = 0; j < 2; ++j) {
                const int s = isUser ? (j == 0 ? 0 : 2) : (j == 0 ? 1 : 3);
                float4 w0 = ldf4(w_vec + (b*4+s)*D + col);
                float4 w1 = ldf4(w_vec + (b*4+s)*D + 64 + col);
                ew[b][j][0]=w0.x*ee[0]; ew[b][j][1]=w0.y*ee[1];
                ew[b][j][2]=w0.z*ee[2]; ew[b][j][3]=w0.w*ee[3];
                ew[b][j][4]=w1.x*ee[4]; ew[b][j][5]=w1.y*ee[5];
                ew[b][j][6]=w1.z*ee[6]; ew[b][j][7]=w1.w*ee[7];
            }
    }

    float acc[6][8];
#pragma unroll
    for (int k = 0; k < 6; ++k)
#pragma unroll
        for (int j = 0; j < 8; ++j) acc[k][j] = 0.f;

    const int quads = (nrows + 3) >> 2;
    const int step  = nb * 4;

    int q  = lb * 4 + wv_;
    int rowA = q * 4 + grp;
    bool vA  = (q < quads) && (rowA < nrows);
    int srcA = vA ? ids[rowA] : 0;
    int qB   = q + step;
    int rowB = qB * 4 + grp;
    bool vB  = (qB < quads) && (rowB < nrows);
    int srcB = vB ? ids[rowB] : 0;

    float xA[8];
    {
        const float* p = emb + (size_t)srcA * D;
        float4 t0 = ldf4(p + col);
        float4 t1 = ldf4(p + 64 + col);
        xA[0]=t0.x; xA[1]=t0.y; xA[2]=t0.z; xA[3]=t0.w;
        xA[4]=t1.x; xA[5]=t1.y; xA[6]=t1.z; xA[7]=t1.w;
    }

    while (q < quads) {
        const int qC   = qB + step;
        const int rowC = qC * 4 + grp;
        const bool vC  = (qC < quads) && (rowC < nrows);
        const int srcC = vC ? ids[rowC] : 0;
        float xB[8];
        {
            const float* p = emb + (size_t)srcB * D;
            float4 t0 = ldf4(p + col);
            float4 t1 = ldf4(p + 64 + col);
            xB[0]=t0.x; xB[1]=t0.y; xB[2]=t0.z; xB[3]=t0.w;
            xB[4]=t1.x; xB[5]=t1.y; xB[6]=t1.z; xB[7]=t1.w;
        }

        float d[3][2];
#pragma unroll
        for (int b = 0; b < 3; ++b)
#pragma unroll
            for (int j = 0; j < 2; ++j) {
                float s = xA[0] * ew[b][j][0];
#pragma unroll
                for (int k = 1; k < 8; ++k) s = fmaf(xA[k], ew[b][j][k], s);
                d[b][j] = row16_allreduce(s);
            }

        if (vA) {
#pragma unroll
            for (int b = 0; b < 3; ++b) {
                const float c0 = d[b][0];
                const float c1 = d[b][1];
#pragma unroll
                for (int j = 0; j < 8; ++j) {
                    acc[b][j]     = fmaf(c0, xA[j], acc[b][j]);
                    acc[3 + b][j] = fmaf(c1, xA[j], acc[3 + b][j]);
                }
            }
        }

        q = qB; qB = qC;
        vA = vB; vB = vC;
        srcB = srcC;
#pragma unroll
        for (int j = 0; j < 8; ++j) xA[j] = xB[j];
    }

    // cross-group reduce within wave (groups hold same cols, different rows)
#pragma unroll
    for (int k = 0; k < 6; ++k)
#pragma unroll
        for (int j = 0; j < 8; ++j) {
            acc[k][j] += __shfl_xor(acc[k][j], 16, 64);
            acc[k][j] += __shfl_xor(acc[k][j], 32, 64);
        }

    __shared__ float lds[4][6][D];
    if (grp == 0) {
#pragma unroll
        for (int k = 0; k < 6; ++k) {
            float4 v0, v1;
            v0.x=acc[k][0]; v0.y=acc[k][1]; v0.z=acc[k][2]; v0.w=acc[k][3];
            v1.x=acc[k][4]; v1.y=acc[k][5]; v1.z=acc[k][6]; v1.w=acc[k][7];
            *reinterpret_cast<float4*>(&lds[wv_][k][col])      = v0;
            *reinterpret_cast<float4*>(&lds[wv_][k][col + 64]) = v1;
        }
    }
    __syncthreads();
    float* pp = partial + (size_t)lb * 768;
    for (int t = threadIdx.x; t < 6 * D; t += 256) {
        const int k = t >> 7, dd = t & 127;
        const float s = (lds[0][k][dd] + lds[1][k][dd])
                      + (lds[2][k][dd] + lds[3][k][dd]);
        pp[t] = s * A_SCALE;
    }
}

// ---------------------------------------------------------------------------
// gmatc: fused combine + matvec. Each of the 12 matvec outputs uses a
// DISTINCT reduction vector v (G1:v=b, G2:v=6+b, H1:v=9+b, H2:v=3+b), so
// each block privately sums its own R-slice from the partials (no inter-
// block dependency). Blocks 12-14: edge rows.
// Phase A: thread (g8,d) sums lb = g8 + 32m + {0,8,16,24} over m<nbx/32
//          == all lb congruent to g8 (mod 8).  [R6 bug: stride was 256]
// Phase B: g8 covers k in [g8*16,(g8+1)*16). Fixed-order LDS trees.
// ---------------------------------------------------------------------------
__global__ __launch_bounds__(1024) void gmatc_kernel(
    const float* __restrict__ pu, const float* __restrict__ pi,
    int nbu, int nbi,
    const float* __restrict__ w_mat, const float* __restrict__ edge_w,
    const float* __restrict__ edge_emb,
    float* __restrict__ G, float* __restrict__ out_edge)
{
    const float mtl[3] = {0.5f, 0.3333333f, 0.1666667f};
    const int blk = blockIdx.x;
    const int d   = threadIdx.x & 127;
    const int g8  = threadIdx.x >> 7;    // 0..7

    __shared__ float red[8][D];
    __shared__ float R_lds[D];

    if (blk < 12) {
        const int b = blk % 3;
        const int grp = blk / 3;          // 0:G1 1:G2 2:H1 3:H2
        int s, v;
        if      (grp == 0) { s = 0; v = b; }
        else if (grp == 1) { s = 1; v = 6 + b; }
        else if (grp == 2) { s = 3; v = 9 + b; }
        else               { s = 2; v = 3 + b; }

        // ---- phase A: R[v][d] = sum_lb partial[lb][v*128+d] ----
        const float* P  = (v < 6) ? pu : pi;
        const int nbx   = (v < 6) ? nbu : nbi;       // both % 32 == 0
        const size_t voff = (size_t)((v < 6) ? v : v - 6) * 128 + d;
        float s0 = 0.f, s1 = 0.f, s2 = 0.f, s3 = 0.f;
        for (int m = 0; m < nbx / 32; ++m) {
            const int base = g8 + 32 * m;            // lb = g8 + 8*(4m+qq)
            s0 += P[(size_t)(base + 0)  * 768 + voff];
            s1 += P[(size_t)(base + 8)  * 768 + voff];
            s2 += P[(size_t)(base + 16) * 768 + voff];
            s3 += P[(size_t)(base + 24) * 768 + voff];
        }
        red[g8][d] = (s0 + s1) + (s2 + s3);
        __syncthreads();
        if (threadIdx.x < 128) {
            float rv = 0.f;
#pragma unroll
            for (int g = 0; g < 8; ++g) rv += red[g][threadIdx.x];
            R_lds[threadIdx.x] = rv;
        }
        __syncthreads();

        // ---- phase B: G[blk][d] = 0.25*mtl[b]*(R . w_mat[b,s][:,d]) ----
        const float* M = w_mat + (size_t)(b * 4 + s) * D * D;
        const int k0 = g8 * 16;
        float t0 = 0.f, t1 = 0.f, t2 = 0.f, t3 = 0.f;
#pragma unroll
        for (int k = k0; k < k0 + 16; k += 4) {
            t0 = fmaf(R_lds[k + 0], M[(size_t)(k + 0) * D + d], t0);
            t1 = fmaf(R_lds[k + 1], M[(size_t)(k + 1) * D + d], t1);
            t2 = fmaf(R_lds[k + 2], M[(size_t)(k + 2) * D + d], t2);
            t3 = fmaf(R_lds[k + 3], M[(size_t)(k + 3) * D + d], t3);
        }
        __syncthreads();                 // red reuse: all prior reads done
        red[g8][d] = (t0 + t1) + (t2 + t3);
        __syncthreads();
        if (threadIdx.x < 128) {
            float sum = 0.f;
#pragma unroll
            for (int g = 0; g < 8; ++g) sum += red[g][threadIdx.x];
            G[blk * D + threadIdx.x] = 0.25f * mtl[b] * sum;
        }
    } else {
        const int b = blk - 12;
        const float* M = edge_w + (size_t)b * D * D;
        const int k0 = g8 * 16;
        float t0 = 0.f, t1 = 0.f, t2 = 0.f, t3 = 0.f;
#pragma unroll
        for (int k = k0; k < k0 + 16; k += 4) {
            t0 = fmaf(edge_emb[k + 0] * B_SCALE, M[(size_t)(k + 0) * D + d], t0);
            t1 = fmaf(edge_emb[k + 1] * B_SCALE, M[(size_t)(k + 1) * D + d], t1);
            t2 = fmaf(edge_emb[k + 2] * B_SCALE, M[(size_t)(k + 2) * D + d], t2);
            t3 = fmaf(edge_emb[k + 3] * B_SCALE, M[(size_t)(k + 3) * D + d], t3);
        }
        red[g8][d] = (t0 + t1) + (t2 + t3);
        __syncthreads();
        if (threadIdx.x < 128) {
            float sum = 0.f;
#pragma unroll
            for (int g = 0; g < 8; ++g) sum += red[g][threadIdx.x];
            out_edge[b * D + threadIdx.x] =
                0.5f * (sum + edge_emb[threadIdx.x] * B_SCALE);
        }
    }
}

// ---------------------------------------------------------------------------
// Pass 2 (merged): out[r,:] = 0.5*A*emb[r,:] + sum_b c0[b]*g[b] + c1[b]*g[3+b]
// with c recomputed in-place from the row (no dots buffer). REVERSE sweep
// (boustrophedon: reads pass1's freshest L3 lines first). Output stores are
// non-temporal so the 256MB stream doesn't evict the embeddings from L3.
// c-dot s-map: user {0,1} (a_xx, a_xyx); item {3,2} (a_yy, a_yxx).
// ---------------------------------------------------------------------------
__global__ __launch_bounds__(256) void pass2_kernel(
    const float* __restrict__ ue, const float* __restrict__ ie,
    const int* __restrict__ uids, const int* __restrict__ iids,
    int U, int I, const float* __restrict__ w_vec,
    const float* __restrict__ edge_emb, const float* __restrict__ G,
    float* __restrict__ out, int nbu, int nbi)
{
    const bool isUser = (int)blockIdx.x < nbu;
    const int lb  = isUser ? blockIdx.x : (blockIdx.x - nbu);
    const int nbx = isUser ? nbu : nbi;
    const float* emb  = isUser ? ue : ie;
    const int* ids    = isUser ? uids : iids;
    const int nrows   = isUser ? U : I;
    const float* g0   = isUser ? G : (G + 6 * D);
    float* dst        = isUser ? out : (out + (size_t)U * D);

    const int lane = threadIdx.x & 63;
    const int grp  = lane >> 4;
    const int li   = lane & 15;
    const int col  = li << 2;
    const int wv_  = threadIdx.x >> 6;

    float ew[3][2][8];
    {
        float4 e0 = ldf4(edge_emb + col);
        float4 e1 = ldf4(edge_emb + 64 + col);
        const float ee[8] = {e0.x*AB, e0.y*AB, e0.z*AB, e0.w*AB,
                             e1.x*AB, e1.y*AB, e1.z*AB, e1.w*AB};
#pragma unroll
        for (int b = 0; b < 3; ++b)
#pragma unroll
            for (int j = 0; j < 2; ++j) {
                const int s = isUser ? (j == 0 ? 0 : 1) : (j == 0 ? 3 : 2);
                float4 w0 = ldf4(w_vec + (b*4+s)*D + col);
                float4 w1 = ldf4(w_vec + (b*4+s)*D + 64 + col);
                ew[b][j][0]=w0.x*ee[0]; ew[b][j][1]=w0.y*ee[1];
                ew[b][j][2]=w0.z*ee[2]; ew[b][j][3]=w0.w*ee[3];
                ew[b][j][4]=w1.x*ee[4]; ew[b][j][5]=w1.y*ee[5];
                ew[b][j][6]=w1.z*ee[6]; ew[b][j][7]=w1.w*ee[7];
            }
    }

    float g[6][8];
#pragma unroll
    for (int k = 0; k < 6; ++k) {
        float4 t0 = ldf4(g0 + k * D + col);
        float4 t1 = ldf4(g0 + k * D + 64 + col);
        g[k][0]=t0.x; g[k][1]=t0.y; g[k][2]=t0.z; g[k][3]=t0.w;
        g[k][4]=t1.x; g[k][5]=t1.y; g[k][6]=t1.z; g[k][7]=t1.w;
    }

    const int quads = (nrows + 3) >> 2;
    const int step  = nbx * 4;

    int ql = lb * 4 + wv_;
    int rA = (quads - 1 - ql) * 4 + grp;
    bool vA = (ql < quads) && (rA < nrows);
    int srcA = vA ? ids[rA] : 0;
    int qlB = ql + step;
    int rB = (quads - 1 - qlB) * 4 + grp;
    bool vB = (qlB < quads) && (rB < nrows);
    int srcB = vB ? ids[rB] : 0;

    float xA[8];
    {
        const float* p = emb + (size_t)srcA * D;
        float4 t0 = ldf4(p + col);
        float4 t1 = ldf4(p + 64 + col);
        xA[0]=t0.x; xA[1]=t0.y; xA[2]=t0.z; xA[3]=t0.w;
        xA[4]=t1.x; xA[5]=t1.y; xA[6]=t1.z; xA[7]=t1.w;
    }

    while (ql < quads) {
        const int qlC = qlB + step;
        const int rC  = (quads - 1 - qlC) * 4 + grp;
        const bool vC = (qlC < quads) && (rC < nrows);
        const int srcC = vC ? ids[rC] : 0;
        float xB[8];
        {
            const float* p = emb + (size_t)srcB * D;
            float4 t0 = ldf4(p + col);
            float4 t1 = ldf4(p + 64 + col);
            xB[0]=t0.x; xB[1]=t0.y; xB[2]=t0.z; xB[3]=t0.w;
            xB[4]=t1.x; xB[5]=t1.y; xB[6]=t1.z; xB[7]=t1.w;
        }

        float d[3][2];
#pragma unroll
        for (int b = 0; b < 3; ++b)
#pragma unroll
            for (int j = 0; j < 2; ++j) {
                float s = xA[0] * ew[b][j][0];
#pragma unroll
                for (int k = 1; k < 8; ++k) s = fmaf(xA[k], ew[b][j][k], s);
                d[b][j] = row16_allreduce(s);
            }

        if (vA) {
            float o[8];
#pragma unroll
            for (int j = 0; j < 8; ++j) o[j] = 0.5f * A_SCALE * xA[j];
#pragma unroll
            for (int b = 0; b < 3; ++b) {
                const float c0 = d[b][0];
                const float c1 = d[b][1];
#pragma unroll
                for (int j = 0; j < 8; ++j) {
                    o[j] = fmaf(c0, g[b][j], o[j]);
                    o[j] = fmaf(c1, g[3 + b][j], o[j]);
                }
            }
            float* op = dst + (size_t)rA * D + col;
            ntst4(op, o[0], o[1], o[2], o[3]);
            ntst4(op + 64, o[4], o[5], o[6], o[7]);
        }

        ql = qlB; qlB = qlC;
        rA = rB; rB = rC;
        vA = vB; vB = vC;
        srcA = srcB; srcB = srcC;
#pragma unroll
        for (int j = 0; j < 8; ++j) xA[j] = xB[j];
    }
}

extern "C" void kernel_launch(void* const* d_in, const int* in_sizes, int n_in,
                              void* d_out, int out_size, void* d_ws, size_t ws_size,
                              hipStream_t stream)
{
    const float* user_emb = (const float*)d_in[0];
    const float* item_emb = (const float*)d_in[1];
    const float* edge_emb = (const float*)d_in[2];
    const float* w_vec    = (const float*)d_in[3];
    const float* w_mat    = (const float*)d_in[4];
    const float* edge_w   = (const float*)d_in[5];
    const int*   user_ids = (const int*)d_in[6];
    const int*   item_ids = (const int*)d_in[7];

    const int U = in_sizes[0] / D;
    const int I = in_sizes[1] / D;

    float* out   = (float*)d_out;
    float* out_e = out + (size_t)(U + I) * D;

    // pass1 block split ~ U:I = 3:2, both multiples of 32 (gmatc unroll)
    const int NBU = 1248, NBI = 800;
    float* ws     = (float*)d_ws;
    float* part_u = ws;                               // NBU*768
    float* part_i = part_u + (size_t)NBU * 768;       // NBI*768
    float* G      = part_i + (size_t)NBI * 768;       // 12*128

    const int NB2U = 1920, NB2I = 1280;

    pass1_kernel<<<NBU + NBI, 256, 0, stream>>>(
        user_emb, item_emb, user_ids, item_ids, U, I, w_vec, edge_emb,
        part_u, part_i, NBU, NBI);
    gmatc_kernel<<<15, 1024, 0, stream>>>(
        part_u, part_i, NBU, NBI, w_mat, edge_w, edge_emb, G, out_e);
    pass2_kernel<<<NB2U + NB2I, 256, 0, stream>>>(
        user_emb, item_emb, user_ids, item_ids, U, I, w_vec, edge_emb,
        G, out, NB2U, NB2I);
}

// Round 9
// 137.988 us; speedup vs baseline: 1.0646x; 1.0646x over previous
//
#include <hip/hip_runtime.h>
#include <cstddef>

#define D 128

static constexpr float A_SCALE = 0.1f;
static constexpr float B_SCALE = 0.1f;
static constexpr float AB = A_SCALE * B_SCALE;   // fold both scales into dot weights

typedef float nfloat4 __attribute__((ext_vector_type(4)));   // native vec for NT builtins

__device__ __forceinline__ float4 ldf4(const float* p) {
    return *reinterpret_cast<const float4*>(p);
}

__device__ __forceinline__ void ntst4(float* p, float a, float b, float c, float d) {
    nfloat4 v; v.x = a; v.y = b; v.z = c; v.w = d;
    __builtin_nontemporal_store(v, reinterpret_cast<nfloat4*>(p));
}

// DPP row-rotate fetch: dst[i] = src[(i+N) mod 16] within each 16-lane row.
// ROW_ROR:N ctrl = 0x120+N. Pure VALU (no DS pipe).
template<int CTRL>
__device__ __forceinline__ float dpp_ror(float x) {
    int xi = __builtin_bit_cast(int, x);
    int yi = __builtin_amdgcn_update_dpp(0, xi, CTRL, 0xF, 0xF, true);
    return __builtin_bit_cast(float, yi);
}

// Rotate-allreduce over a 16-lane row: rotations by 1,2,4,8 -> every lane
// holds the 16-lane sum. 8 VALU ops, zero DS ops.
__device__ __forceinline__ float row16_allreduce(float v) {
    v += dpp_ror<0x121>(v);
    v += dpp_ror<0x122>(v);
    v += dpp_ror<0x124>(v);
    v += dpp_ror<0x128>(v);
    return v;
}

// ---------------------------------------------------------------------------
// Pass 1 (merged user+item): global reduction partials only (dots are
// recomputed in pass 2 -- no dots round-trip).
// Wave layout: 16 lanes x 8 floats per row -> wave = 4 rows/iter. FORWARD
// sweep. Block split user:item = 1216:832 (both %64 for combine ILP;
// per-block rows 247 vs 240 -> balanced finish).
// 6 dots/4-rows: user s={0,2} (a_xx, a_yxy), item s={1,3} (a_xyy, a_yy).
// acc[b] pairs d[b][0], acc[3+b] pairs d[b][1] (raw-x accumulation, A_SCALE
// applied at partial write). partial layout: partial[lb][t], contiguous 3KB.
// ---------------------------------------------------------------------------
__global__ __launch_bounds__(256) void pass1_kernel(
    const float* __restrict__ ue, const float* __restrict__ ie,
    const int* __restrict__ uids, const int* __restrict__ iids,
    int U, int I, const float* __restrict__ w_vec,
    const float* __restrict__ edge_emb,
    float* __restrict__ part_u, float* __restrict__ part_i,
    int nbu, int nbi)
{
    const bool isUser = (int)blockIdx.x < nbu;
    const int lb = isUser ? blockIdx.x : (blockIdx.x - nbu);
    const int nb = isUser ? nbu : nbi;
    const float* emb = isUser ? ue : ie;
    const int* ids   = isUser ? uids : iids;
    const int nrows  = isUser ? U : I;
    float* partial   = isUser ? part_u : part_i;

    const int lane = threadIdx.x & 63;
    const int grp  = lane >> 4;          // row within quad
    const int li   = lane & 15;
    const int col  = li << 2;            // cols [col,col+4) and [col+64,col+68)
    const int wv_  = threadIdx.x >> 6;   // wave in block

    // ew[b][j][k] = w_vec[b][s][k] * e_raw[k] * A*B
    float ew[3][2][8];
    {
        float4 e0 = ldf4(edge_emb + col);
        float4 e1 = ldf4(edge_emb + 64 + col);
        const float ee[8] = {e0.x*AB, e0.y*AB, e0.z*AB, e0.w*AB,
                             e1.x*AB, e1.y*AB, e1.z*AB, e1.w*AB};
#pragma unroll
        for (int b = 0; b < 3; ++b)
#pragma unroll
            for (int j = 0; j < 2; ++j) {
                const int s = isUser ? (j == 0 ? 0 : 2) : (j == 0 ? 1 : 3);
                float4 w0 = ldf4(w_vec + (b*4+s)*D + col);
                float4 w1 = ldf4(w_vec + (b*4+s)*D + 64 + col);
                ew[b][j][0]=w0.x*ee[0]; ew[b][j][1]=w0.y*ee[1];
                ew[b][j][2]=w0.z*ee[2]; ew[b][j][3]=w0.w*ee[3];
                ew[b][j][4]=w1.x*ee[4]; ew[b][j][5]=w1.y*ee[5];
                ew[b][j][6]=w1.z*ee[6]; ew[b][j][7]=w1.w*ee[7];
            }
    }

    float acc[6][8];
#pragma unroll
    for (int k = 0; k < 6; ++k)
#pragma unroll
        for (int j = 0; j < 8; ++j) acc[k][j] = 0.f;

    const int quads = (nrows + 3) >> 2;
    const int step  = nb * 4;

    int q  = lb * 4 + wv_;
    int rowA = q * 4 + grp;
    bool vA  = (q < quads) && (rowA < nrows);
    int srcA = vA ? ids[rowA] : 0;
    int qB   = q + step;
    int rowB = qB * 4 + grp;
    bool vB  = (qB < quads) && (rowB < nrows);
    int srcB = vB ? ids[rowB] : 0;

    float xA[8];
    {
        const float* p = emb + (size_t)srcA * D;
        float4 t0 = ldf4(p + col);
        float4 t1 = ldf4(p + 64 + col);
        xA[0]=t0.x; xA[1]=t0.y; xA[2]=t0.z; xA[3]=t0.w;
        xA[4]=t1.x; xA[5]=t1.y; xA[6]=t1.z; xA[7]=t1.w;
    }

    while (q < quads) {
        const int qC   = qB + step;
        const int rowC = qC * 4 + grp;
        const bool vC  = (qC < quads) && (rowC < nrows);
        const int srcC = vC ? ids[rowC] : 0;
        float xB[8];
        {
            const float* p = emb + (size_t)srcB * D;
            float4 t0 = ldf4(p + col);
            float4 t1 = ldf4(p + 64 + col);
            xB[0]=t0.x; xB[1]=t0.y; xB[2]=t0.z; xB[3]=t0.w;
            xB[4]=t1.x; xB[5]=t1.y; xB[6]=t1.z; xB[7]=t1.w;
        }

        float d[3][2];
#pragma unroll
        for (int b = 0; b < 3; ++b)
#pragma unroll
            for (int j = 0; j < 2; ++j) {
                float s = xA[0] * ew[b][j][0];
#pragma unroll
                for (int k = 1; k < 8; ++k) s = fmaf(xA[k], ew[b][j][k], s);
                d[b][j] = row16_allreduce(s);
            }

        if (vA) {
#pragma unroll
            for (int b = 0; b < 3; ++b) {
                const float c0 = d[b][0];
                const float c1 = d[b][1];
#pragma unroll
                for (int j = 0; j < 8; ++j) {
                    acc[b][j]     = fmaf(c0, xA[j], acc[b][j]);
                    acc[3 + b][j] = fmaf(c1, xA[j], acc[3 + b][j]);
                }
            }
        }

        q = qB; qB = qC;
        vA = vB; vB = vC;
        srcB = srcC;
#pragma unroll
        for (int j = 0; j < 8; ++j) xA[j] = xB[j];
    }

    // cross-group reduce within wave (groups hold same cols, different rows)
#pragma unroll
    for (int k = 0; k < 6; ++k)
#pragma unroll
        for (int j = 0; j < 8; ++j) {
            acc[k][j] += __shfl_xor(acc[k][j], 16, 64);
            acc[k][j] += __shfl_xor(acc[k][j], 32, 64);
        }

    __shared__ float lds[4][6][D];
    if (grp == 0) {
#pragma unroll
        for (int k = 0; k < 6; ++k) {
            float4 v0, v1;
            v0.x=acc[k][0]; v0.y=acc[k][1]; v0.z=acc[k][2]; v0.w=acc[k][3];
            v1.x=acc[k][4]; v1.y=acc[k][5]; v1.z=acc[k][6]; v1.w=acc[k][7];
            *reinterpret_cast<float4*>(&lds[wv_][k][col])      = v0;
            *reinterpret_cast<float4*>(&lds[wv_][k][col + 64]) = v1;
        }
    }
    __syncthreads();
    float* pp = partial + (size_t)lb * 768;
    for (int t = threadIdx.x; t < 6 * D; t += 256) {
        const int k = t >> 7, dd = t & 127;
        const float s = (lds[0][k][dd] + lds[1][k][dd])
                      + (lds[2][k][dd] + lds[3][k][dd]);
        pp[t] = s * A_SCALE;
    }
}

// ---------------------------------------------------------------------------
// Combine: 96 blocks; block handles 16 consecutive t. Thread (j=tid>>4,
// tt=tid&15) sums slabs lb ≡ j (mod 16) with 4-deep load ILP (needs
// nbu,nbi % 64 == 0). Fixed-order LDS tree -> deterministic.
// R[v*128+d]: v 0..2 a_xx@x0, 3..5 a_yxy@x0, 6..8 a_xyy@y0, 9..11 a_yy@y0
// ---------------------------------------------------------------------------
__global__ __launch_bounds__(256) void combine_kernel(
    const float* __restrict__ pu, const float* __restrict__ pi,
    int nbu, int nbi, float* __restrict__ R)
{
    const int T  = blockIdx.x * 16;          // 0..1535 in steps of 16
    const int tt = threadIdx.x & 15;
    const int j  = threadIdx.x >> 4;         // 0..15
    const float* P;
    int nbx, toff;
    if (T < 768) { P = pu; nbx = nbu; toff = T; }
    else         { P = pi; nbx = nbi; toff = T - 768; }

    float s0 = 0.f, s1 = 0.f, s2 = 0.f, s3 = 0.f;
    for (int m = j; m < nbx; m += 64) {
        s0 += P[(size_t)(m +  0) * 768 + toff + tt];
        s1 += P[(size_t)(m + 16) * 768 + toff + tt];
        s2 += P[(size_t)(m + 32) * 768 + toff + tt];
        s3 += P[(size_t)(m + 48) * 768 + toff + tt];
    }

    __shared__ float red[16][16];
    red[j][tt] = (s0 + s1) + (s2 + s3);
    __syncthreads();
    if (threadIdx.x < 16) {
        float r = 0.f;
#pragma unroll
        for (int g = 0; g < 16; ++g) r += red[g][threadIdx.x];
        R[T + threadIdx.x] = r;
    }
}

// ---------------------------------------------------------------------------
// gmat: 51 blocks. Blocks 0..47: matvec m=blk>>2, d-quarter qd=blk&3;
// k split 8-way across waves (16 k each), LDS tree. Blocks 48..50: edges.
// ---------------------------------------------------------------------------
__global__ __launch_bounds__(256) void gmat_kernel(
    const float* __restrict__ R, const float* __restrict__ w_mat,
    const float* __restrict__ edge_w, const float* __restrict__ edge_emb,
    float* __restrict__ G, float* __restrict__ out_edge)
{
    __shared__ float red[256];
    const int blk = blockIdx.x;

    if (blk < 48) {
        const float mtl[3] = {0.5f, 0.3333333f, 0.1666667f};
        const int m  = blk >> 2;             // matvec 0..11
        const int qd = blk & 3;              // d-quarter
        const int b = m % 3, gg = m / 3;     // 0:G1 1:G2 2:H1 3:H2
        int s, v;
        if      (gg == 0) { s = 0; v = b; }
        else if (gg == 1) { s = 1; v = 6 + b; }
        else if (gg == 2) { s = 3; v = 9 + b; }
        else              { s = 2; v = 3 + b; }
        const int dl = threadIdx.x & 31;
        const int d  = qd * 32 + dl;
        const int kk = threadIdx.x >> 5;     // 0..7, 16 k each
        const float* M = w_mat + (size_t)(b * 4 + s) * D * D;
        const float* r = R + v * D;
        float t = 0.f;
#pragma unroll
        for (int k = kk * 16; k < kk * 16 + 16; ++k)
            t = fmaf(r[k], M[(size_t)k * D + d], t);
        red[kk * 32 + dl] = t;
        __syncthreads();
        if (threadIdx.x < 32) {
            float sum = 0.f;
#pragma unroll
            for (int g = 0; g < 8; ++g) sum += red[g * 32 + threadIdx.x];
            G[m * D + qd * 32 + threadIdx.x] = 0.25f * mtl[b] * sum;
        }
    } else {
        const int b = blk - 48;
        const int d = threadIdx.x & 127;
        const int h = threadIdx.x >> 7;      // 0,1 : k-half
        const float* M = edge_w + (size_t)b * D * D;
        const float* e = edge_emb + h * 64;
        float t0 = 0.f, t1 = 0.f, t2 = 0.f, t3 = 0.f;
#pragma unroll 4
        for (int k = 0; k < 64; k += 4) {
            t0 = fmaf(e[k + 0] * B_SCALE, M[(size_t)(h * 64 + k + 0) * D + d], t0);
            t1 = fmaf(e[k + 1] * B_SCALE, M[(size_t)(h * 64 + k + 1) * D + d], t1);
            t2 = fmaf(e[k + 2] * B_SCALE, M[(size_t)(h * 64 + k + 2) * D + d], t2);
            t3 = fmaf(e[k + 3] * B_SCALE, M[(size_t)(h * 64 + k + 3) * D + d], t3);
        }
        red[h * 128 + d] = (t0 + t1) + (t2 + t3);
        __syncthreads();
        if (threadIdx.x < 128) {
            out_edge[b * D + threadIdx.x] =
                0.5f * ((red[threadIdx.x] + red[128 + threadIdx.x])
                        + edge_emb[threadIdx.x] * B_SCALE);
        }
    }
}

// ---------------------------------------------------------------------------
// Pass 2 (merged): out[r,:] = 0.5*A*emb[r,:] + sum_b c0[b]*g[b] + c1[b]*g[3+b]
// with c recomputed in-place from the row (no dots buffer). REVERSE sweep
// (boustrophedon: reads pass1's freshest L3 lines first). Output stores are
// non-temporal so the 256MB stream doesn't evict the embeddings from L3.
// c-dot s-map: user {0,1} (a_xx, a_xyx); item {3,2} (a_yy, a_yxx).
// ---------------------------------------------------------------------------
__global__ __launch_bounds__(256) void pass2_kernel(
    const float* __restrict__ ue, const float* __restrict__ ie,
    const int* __restrict__ uids, const int* __restrict__ iids,
    int U, int I, const float* __restrict__ w_vec,
    const float* __restrict__ edge_emb, const float* __restrict__ G,
    float* __restrict__ out, int nbu, int nbi)
{
    const bool isUser = (int)blockIdx.x < nbu;
    const int lb  = isUser ? blockIdx.x : (blockIdx.x - nbu);
    const int nbx = isUser ? nbu : nbi;
    const float* emb  = isUser ? ue : ie;
    const int* ids    = isUser ? uids : iids;
    const int nrows   = isUser ? U : I;
    const float* g0   = isUser ? G : (G + 6 * D);
    float* dst        = isUser ? out : (out + (size_t)U * D);

    const int lane = threadIdx.x & 63;
    const int grp  = lane >> 4;
    const int li   = lane & 15;
    const int col  = li << 2;
    const int wv_  = threadIdx.x >> 6;

    float ew[3][2][8];
    {
        float4 e0 = ldf4(edge_emb + col);
        float4 e1 = ldf4(edge_emb + 64 + col);
        const float ee[8] = {e0.x*AB, e0.y*AB, e0.z*AB, e0.w*AB,
                             e1.x*AB, e1.y*AB, e1.z*AB, e1.w*AB};
#pragma unroll
        for (int b = 0; b < 3; ++b)
#pragma unroll
            for (int j = 0; j < 2; ++j) {
                const int s = isUser ? (j == 0 ? 0 : 1) : (j == 0 ? 3 : 2);
                float4 w0 = ldf4(w_vec + (b*4+s)*D + col);
                float4 w1 = ldf4(w_vec + (b*4+s)*D + 64 + col);
                ew[b][j][0]=w0.x*ee[0]; ew[b][j][1]=w0.y*ee[1];
                ew[b][j][2]=w0.z*ee[2]; ew[b][j][3]=w0.w*ee[3];
                ew[b][j][4]=w1.x*ee[4]; ew[b][j][5]=w1.y*ee[5];
                ew[b][j][6]=w1.z*ee[6]; ew[b][j][7]=w1.w*ee[7];
            }
    }

    float g[6][8];
#pragma unroll
    for (int k = 0; k < 6; ++k) {
        float4 t0 = ldf4(g0 + k * D + col);
        float4 t1 = ldf4(g0 + k * D + 64 + col);
        g[k][0]=t0.x; g[k][1]=t0.y; g[k][2]=t0.z; g[k][3]=t0.w;
        g[k][4]=t1.x; g[k][5]=t1.y; g[k][6]=t1.z; g[k][7]=t1.w;
    }

    const int quads = (nrows + 3) >> 2;
    const int step  = nbx * 4;

    int ql = lb * 4 + wv_;
    int rA = (quads - 1 - ql) * 4 + grp;
    bool vA = (ql < quads) && (rA < nrows);
    int srcA = vA ? ids[rA] : 0;
    int qlB = ql + step;
    int rB = (quads - 1 - qlB) * 4 + grp;
    bool vB = (qlB < quads) && (rB < nrows);
    int srcB = vB ? ids[rB] : 0;

    float xA[8];
    {
        const float* p = emb + (size_t)srcA * D;
        float4 t0 = ldf4(p + col);
        float4 t1 = ldf4(p + 64 + col);
        xA[0]=t0.x; xA[1]=t0.y; xA[2]=t0.z; xA[3]=t0.w;
        xA[4]=t1.x; xA[5]=t1.y; xA[6]=t1.z; xA[7]=t1.w;
    }

    while (ql < quads) {
        const int qlC = qlB + step;
        const int rC  = (quads - 1 - qlC) * 4 + grp;
        const bool vC = (qlC < quads) && (rC < nrows);
        const int srcC = vC ? ids[rC] : 0;
        float xB[8];
        {
            const float* p = emb + (size_t)srcB * D;
            float4 t0 = ldf4(p + col);
            float4 t1 = ldf4(p + 64 + col);
            xB[0]=t0.x; xB[1]=t0.y; xB[2]=t0.z; xB[3]=t0.w;
            xB[4]=t1.x; xB[5]=t1.y; xB[6]=t1.z; xB[7]=t1.w;
        }

        float d[3][2];
#pragma unroll
        for (int b = 0; b < 3; ++b)
#pragma unroll
            for (int j = 0; j < 2; ++j) {
                float s = xA[0] * ew[b][j][0];
#pragma unroll
                for (int k = 1; k < 8; ++k) s = fmaf(xA[k], ew[b][j][k], s);
                d[b][j] = row16_allreduce(s);
            }

        if (vA) {
            float o[8];
#pragma unroll
            for (int j = 0; j < 8; ++j) o[j] = 0.5f * A_SCALE * xA[j];
#pragma unroll
            for (int b = 0; b < 3; ++b) {
                const float c0 = d[b][0];
                const float c1 = d[b][1];
#pragma unroll
                for (int j = 0; j < 8; ++j) {
                    o[j] = fmaf(c0, g[b][j], o[j]);
                    o[j] = fmaf(c1, g[3 + b][j], o[j]);
                }
            }
            float* op = dst + (size_t)rA * D + col;
            ntst4(op, o[0], o[1], o[2], o[3]);
            ntst4(op + 64, o[4], o[5], o[6], o[7]);
        }

        ql = qlB; qlB = qlC;
        rA = rB; rB = rC;
        vA = vB; vB = vC;
        srcA = srcB; srcB = srcC;
#pragma unroll
        for (int j = 0; j < 8; ++j) xA[j] = xB[j];
    }
}

extern "C" void kernel_launch(void* const* d_in, const int* in_sizes, int n_in,
                              void* d_out, int out_size, void* d_ws, size_t ws_size,
                              hipStream_t stream)
{
    const float* user_emb = (const float*)d_in[0];
    const float* item_emb = (const float*)d_in[1];
    const float* edge_emb = (const float*)d_in[2];
    const float* w_vec    = (const float*)d_in[3];
    const float* w_mat    = (const float*)d_in[4];
    const float* edge_w   = (const float*)d_in[5];
    const int*   user_ids = (const int*)d_in[6];
    const int*   item_ids = (const int*)d_in[7];

    const int U = in_sizes[0] / D;
    const int I = in_sizes[1] / D;

    float* out   = (float*)d_out;
    float* out_e = out + (size_t)(U + I) * D;

    // pass1 split: both %64 (combine ILP); per-block rows 247 vs 240.
    const int NBU = 1216, NBI = 832;
    float* ws     = (float*)d_ws;
    float* part_u = ws;                               // NBU*768
    float* part_i = part_u + (size_t)NBU * 768;       // NBI*768
    float* R      = part_i + (size_t)NBI * 768;       // 1536
    float* G      = R + 1536;                         // 12*128

    const int NB2U = 1920, NB2I = 1280;

    pass1_kernel<<<NBU + NBI, 256, 0, stream>>>(
        user_emb, item_emb, user_ids, item_ids, U, I, w_vec, edge_emb,
        part_u, part_i, NBU, NBI);
    combine_kernel<<<96, 256, 0, stream>>>(part_u, part_i, NBU, NBI, R);
    gmat_kernel<<<51, 256, 0, stream>>>(R, w_mat, edge_w, edge_emb, G, out_e);
    pass2_kernel<<<NB2U + NB2I, 256, 0, stream>>>(
        user_emb, item_emb, user_ids, item_ids, U, I, w_vec, edge_emb,
        G, out, NB2U, NB2I);
}